// Round 14
// baseline (76.239 us; speedup 1.0000x reference)
//
#include <hip/hip_runtime.h>
#include <stdint.h>

#define NE    7
#define DD    64
#define NDC   3
#define BLOCK 256
#define ROWS  128        // rows per k1 block; B = 2048*128
#define NFRAG 18
#define NSUB  8
#define NBIN  (NE*NSUB)  // 56 bins
#define CAP   5120       // rows per bin (mean 4681, sigma 63 -> +7 sigma)
// ws layout (dwords):
#define WOFF  64                       // hdr: 56 counters (+pad). then packed W: 7*18*64*4
#define BOFF  40960                    // bins: NBIN*CAP*32 dw (fragment-slot order)
#define IOFF  (BOFF + NBIN*CAP*32)     // ids:  NBIN*CAP dw

typedef __fp16   half8 __attribute__((ext_vector_type(8)));
typedef float    f32x4 __attribute__((ext_vector_type(4)));
typedef uint32_t u32x4 __attribute__((ext_vector_type(4)));
typedef uint32_t u32x2 __attribute__((ext_vector_type(2)));
typedef __fp16   h2_t  __attribute__((ext_vector_type(2)));

__device__ __forceinline__ uint32_t pkrtz(float a, float b) {
  h2_t h = __builtin_amdgcn_cvt_pkrtz(a, b);
  return __builtin_bit_cast(uint32_t, h);
}
__device__ __forceinline__ f32x4 mfma16(u32x4 a, u32x4 b, f32x4 c) {
  return __builtin_amdgcn_mfma_f32_16x16x32_f16(
      __builtin_bit_cast(half8, a), __builtin_bit_cast(half8, b), c, 0, 0, 0);
}
__device__ __forceinline__ u32x4 relu_pack(f32x4 lo, f32x4 hi) {
  u32x4 t = { pkrtz(fmaxf(lo[0],0.f), fmaxf(lo[1],0.f)),
              pkrtz(fmaxf(lo[2],0.f), fmaxf(lo[3],0.f)),
              pkrtz(fmaxf(hi[0],0.f), fmaxf(hi[1],0.f)),
              pkrtz(fmaxf(hi[2],0.f), fmaxf(hi[3],0.f)) };
  return t;
}

// ---- pack W^T -> A-fragment layout (HW-verified R4), LDS-staged; zero hdr ----
__global__ __launch_bounds__(BLOCK) void pack_w2(
    const float* __restrict__ W1, const float* __restrict__ W2,
    const float* __restrict__ W3, uint32_t* __restrict__ ws) {
  __shared__ float wt[DD*DD];
  const int blk = blockIdx.x;
  if (blk == 0 && threadIdx.x < WOFF) ws[threadIdx.x] = 0;   // zero bin counters
  const int e = blk >> 1, half = blk & 1;
  const float* Wsrc = (half ? W2 : W1) + (size_t)e*DD*DD;

  const float4* s4 = (const float4*)Wsrc;
  float4* d4 = (float4*)wt;
  #pragma unroll
  for (int i = 0; i < DD*DD/4/BLOCK; ++i)
    d4[i*BLOCK + threadIdx.x] = s4[i*BLOCK + threadIdx.x];
  __syncthreads();

  for (int idx = threadIdx.x; idx < 8*64; idx += BLOCK) {
    const int fl = idx >> 6, l = idx & 63;
    const int nt = fl >> 1, ks = fl & 1;
    const int n  = nt*16 + (l & 15), g = l >> 4;
    uint32_t dst[4];
    #pragma unroll
    for (int d = 0; d < 4; ++d) {
      float v[2];
      #pragma unroll
      for (int h = 0; h < 2; ++h) {
        const int kk = 16*(d>>1) + 4*g + 2*(d&1) + h;
        v[h] = wt[(32*ks + kk)*DD + n];
      }
      dst[d] = pkrtz(v[0], v[1]);
    }
    uint32_t* p = ws + WOFF + ((size_t)(e*NFRAG + half*8 + fl)*64 + l)*4;
    p[0]=dst[0]; p[1]=dst[1]; p[2]=dst[2]; p[3]=dst[3];
  }

  if (half == 0) {
    const float* Wl2 = W3 + (size_t)e*DD*NDC;
    for (int idx = threadIdx.x; idx < 2*64; idx += BLOCK) {
      const int ks = idx >> 6, l = idx & 63;
      const int n  = l & 15, g = l >> 4;
      uint32_t dst[4];
      #pragma unroll
      for (int d = 0; d < 4; ++d) {
        float v[2];
        #pragma unroll
        for (int h = 0; h < 2; ++h) {
          const int kk = 16*(d>>1) + 4*g + 2*(d&1) + h;
          v[h] = (n < NDC) ? Wl2[(32*ks + kk)*NDC + n] : 0.0f;
        }
        dst[d] = pkrtz(v[0], v[1]);
      }
      uint32_t* p = ws + WOFF + ((size_t)(e*NFRAG + 16 + ks)*64 + l)*4;
      p[0]=dst[0]; p[1]=dst[1]; p[2]=dst[2]; p[3]=dst[3];
    }
  }
}

// ---- k1: coalesced X read -> fragment pack -> ballot sort -> binned global write ----
__global__ __launch_bounds__(BLOCK) void k1_bin(
    const float* __restrict__ X, const int* __restrict__ S,
    uint32_t* __restrict__ ws)
{
  __shared__ __align__(16) uint32_t pk[ROWS*32];   // 16 KB fragment-slot packed X
  __shared__ uint16_t srt[ROWS];
  __shared__ uint8_t  srtE[ROWS];
  __shared__ int wcnt[2][NE], woff[2][NE], cnt[NE], bbase[NE];

  const int tid = threadIdx.x, wv = tid >> 6, lane = tid & 63;
  const int base = blockIdx.x * ROWS;
  const int sub  = blockIdx.x & (NSUB - 1);

  // route ballots (waves 0-1 own the 128 rows)
  int e_i = 0, myprefix = 0;
  if (wv < 2) {
    e_i = S[base + tid];
    unsigned long long mk[NE];
    #pragma unroll
    for (int e = 0; e < NE; ++e) mk[e] = __ballot(e_i == e);
    #pragma unroll
    for (int e = 0; e < NE; ++e)
      if (e_i == e) myprefix = __popcll(mk[e] & ((1ull << lane) - 1ull));
    if (lane < NE) wcnt[wv][lane] = __popcll(mk[lane]);
  }

  // X -> pk (1-KB contiguous per instr), fragment-slot layout, bank-swizzled
  {
    const float4* Xb = (const float4*)(X + (size_t)base * DD);
    const int q     = lane & 15;
    const int rsub  = lane >> 4;
    const int slotq = 4*(q >> 3) + (q & 3);
    const int hq    = (q >> 2) & 1;
    #pragma unroll
    for (int it = 0; it < 8; ++it) {
      const int r = wv*32 + it*4 + rsub;
      const float4 v = Xb[r*16 + q];
      u32x2 w2 = { pkrtz(v.x, v.y), pkrtz(v.z, v.w) };
      *(u32x2*)&pk[r*32 + ((slotq ^ (r & 7)) << 2) + hq*2] = w2;
    }
  }
  __syncthreads();

  if (tid == 0) {
    int acc = 0;
    for (int e = 0; e < NE; ++e) {
      const int s0 = acc;
      for (int w = 0; w < 2; ++w) { woff[w][e] = acc; acc += wcnt[w][e]; }
      cnt[e] = acc - s0;
    }
  }
  __syncthreads();

  if (tid < NE) bbase[tid] = atomicAdd((int*)ws + tid*NSUB + sub, cnt[tid]);
  if (tid < ROWS) {
    srt [woff[wv][e_i] + myprefix] = (uint16_t)tid;
    srtE[woff[wv][e_i] + myprefix] = (uint8_t)e_i;
  }
  __syncthreads();

  // bin write: 2 threads per sorted row, 64 B each (contiguous runs per expert)
  {
    const int i  = tid >> 1, hh = tid & 1;
    const int lr = srt[i];
    const int ee = srtE[i];
    const int slot = bbase[ee] + (i - woff[0][ee]);
    uint32_t* dstb = ws + BOFF + ((size_t)(ee*NSUB + sub)*CAP + slot)*32;
    #pragma unroll
    for (int j = 0; j < 4; ++j) {
      const int ls = hh*4 + j;
      const u32x4 v = *(const u32x4*)&pk[lr*32 + ((ls ^ (lr & 7)) << 2)];
      *(u32x4*)(dstb + ls*4) = v;
    }
  }
  if (tid < ROWS) {
    const int ee = srtE[tid];
    const int slot = bbase[ee] + (tid - woff[0][ee]);
    ws[IOFF + (size_t)(ee*NSUB + sub)*CAP + slot] = base + srt[tid];
  }
}

// ---- k2: uniform-expert MFMA; contiguous fragment reads; af once in VGPR ----
__global__ __launch_bounds__(BLOCK) void k2_mlp(
    const uint32_t* __restrict__ ws,
    const float* __restrict__ b1, const float* __restrict__ b2,
    const float* __restrict__ b3,
    float* __restrict__ out, int B)
{
  const int bin = blockIdx.y;
  const int e   = bin >> 3;
  const int cn  = ((const int*)ws)[bin];
  const int tid = threadIdx.x;
  const int wv = tid >> 6, lane = tid & 63;
  const int r15 = lane & 15, g = lane >> 4;
  const int rel0 = blockIdx.x*128 + wv*32;
  if (rel0 >= cn) return;

  const uint32_t* bdat = ws + BOFF + (size_t)bin*CAP*32;
  const int*      ids  = (const int*)ws + IOFF + (size_t)bin*CAP;

  const int m   = min(32, cn - rel0);
  const int njt = (m > 16) ? 2 : 1;

  // contiguous fragment + id reads (clamped tail; no prefill needed)
  int rid[2];
  u32x4 xf[2][2];
  #pragma unroll
  for (int jt = 0; jt < 2; ++jt) {
    if (jt >= njt) break;
    const int rr = min(rel0 + jt*16 + r15, cn - 1);
    rid[jt] = ids[rr];
    xf[jt][0] = *(const u32x4*)(bdat + (size_t)rr*32 + g*4);
    xf[jt][1] = *(const u32x4*)(bdat + (size_t)rr*32 + (4 + g)*4);
  }

  // resident A-fragments (once per block)
  const u32x4* wse = (const u32x4*)(ws + WOFF) + (size_t)e*NFRAG*64;
  u32x4 af[NFRAG];
  #pragma unroll
  for (int f = 0; f < NFRAG; ++f) af[f] = wse[f*64 + lane];

  // Layer 1
  f32x4 c[4][2];
  #pragma unroll
  for (int nt = 0; nt < 4; ++nt) {
    const float4 bv = *(const float4*)(b1 + e*DD + nt*16 + 4*g);
    #pragma unroll
    for (int jt = 0; jt < 2; ++jt) {
      if (jt >= njt) break;
      f32x4 acc = { bv.x, bv.y, bv.z, bv.w };
      acc = mfma16(af[nt*2+0], xf[jt][0], acc);
      acc = mfma16(af[nt*2+1], xf[jt][1], acc);
      c[nt][jt] = acc;
    }
  }
  u32x4 hf[2][2];
  #pragma unroll
  for (int jt = 0; jt < 2; ++jt) {
    if (jt >= njt) break;
    hf[jt][0] = relu_pack(c[0][jt], c[1][jt]);
    hf[jt][1] = relu_pack(c[2][jt], c[3][jt]);
  }

  // Layer 2
  #pragma unroll
  for (int nt = 0; nt < 4; ++nt) {
    const float4 bv = *(const float4*)(b2 + e*DD + nt*16 + 4*g);
    #pragma unroll
    for (int jt = 0; jt < 2; ++jt) {
      if (jt >= njt) break;
      f32x4 acc = { bv.x, bv.y, bv.z, bv.w };
      acc = mfma16(af[8+nt*2+0], hf[jt][0], acc);
      acc = mfma16(af[8+nt*2+1], hf[jt][1], acc);
      c[nt][jt] = acc;
    }
  }
  u32x4 tf[2][2];
  #pragma unroll
  for (int jt = 0; jt < 2; ++jt) {
    if (jt >= njt) break;
    tf[jt][0] = relu_pack(c[0][jt], c[1][jt]);
    tf[jt][1] = relu_pack(c[2][jt], c[3][jt]);
  }

  // Layer 3 + softmax; scattered 12-B stores at the very end (non-blocking)
  const float bb0 = b3[e*NDC+0], bb1 = b3[e*NDC+1], bb2 = b3[e*NDC+2];
  #pragma unroll
  for (int jt = 0; jt < 2; ++jt) {
    if (jt >= njt) break;
    f32x4 acc = { bb0, bb1, bb2, 0.f };
    acc = mfma16(af[16], tf[jt][0], acc);
    acc = mfma16(af[17], tf[jt][1], acc);
    if (g == 0 && (jt*16 + r15) < m) {
      const int row = rid[jt];
      const float l0 = acc[0], l1 = acc[1], l2 = acc[2];
      const float mx  = fmaxf(l0, fmaxf(l1, l2));
      const float p0  = __expf(l0 - mx);
      const float p1  = __expf(l1 - mx);
      const float p2  = __expf(l2 - mx);
      const float inv = 1.0f / (p0 + p1 + p2);
      float* o = out + (size_t)row*3;
      o[0] = l0; o[1] = l1; o[2] = l2;
      float* pr = out + (size_t)B*3 + (size_t)row*3;
      pr[0] = p0*inv; pr[1] = p1*inv; pr[2] = p2*inv;
    }
  }
}

extern "C" void kernel_launch(void* const* d_in, const int* in_sizes, int n_in,
                              void* d_out, int out_size, void* d_ws, size_t ws_size,
                              hipStream_t stream)
{
  const float* X  = (const float*)d_in[0];
  const int*   S  = (const int*)d_in[1];
  const float* W1 = (const float*)d_in[2];
  const float* B1 = (const float*)d_in[3];
  const float* W2 = (const float*)d_in[4];
  const float* B2 = (const float*)d_in[5];
  const float* W3 = (const float*)d_in[6];
  const float* B3 = (const float*)d_in[7];
  float* out = (float*)d_out;
  uint32_t* ws = (uint32_t*)d_ws;

  const int B = in_sizes[0] / DD;   // 262144

  pack_w2<<<NE*2, BLOCK, 0, stream>>>(W1, W2, W3, ws);
  k1_bin <<<B / ROWS, BLOCK, 0, stream>>>(X, S, ws);
  k2_mlp <<<dim3(CAP/128, NBIN), BLOCK, 0, stream>>>(ws, B1, B2, B3, out, B);
}

// Round 15
// 41.935 us; speedup vs baseline: 1.8180x; 1.8180x over previous
//
#include <hip/hip_runtime.h>
#include <stdint.h>

#define NE    7
#define DD    64
#define NDC   3
#define BLOCK 256
#define ROWS  128       // rows per chunk; 2 chunks per block; B = 1024*256
#define NFRAG 18

typedef __fp16   half8 __attribute__((ext_vector_type(8)));
typedef float    f32x4 __attribute__((ext_vector_type(4)));
typedef uint32_t u32x4 __attribute__((ext_vector_type(4)));
typedef uint32_t u32x2 __attribute__((ext_vector_type(2)));
typedef __fp16   h2_t  __attribute__((ext_vector_type(2)));

__device__ __forceinline__ uint32_t pkrtz(float a, float b) {
  h2_t h = __builtin_amdgcn_cvt_pkrtz(a, b);
  return __builtin_bit_cast(uint32_t, h);
}
__device__ __forceinline__ f32x4 mfma16(u32x4 a, u32x4 b, f32x4 c) {
  return __builtin_amdgcn_mfma_f32_16x16x32_f16(
      __builtin_bit_cast(half8, a), __builtin_bit_cast(half8, b), c, 0, 0, 0);
}
__device__ __forceinline__ u32x4 relu_pack(f32x4 lo, f32x4 hi) {
  u32x4 t = { pkrtz(fmaxf(lo[0],0.f), fmaxf(lo[1],0.f)),
              pkrtz(fmaxf(lo[2],0.f), fmaxf(lo[3],0.f)),
              pkrtz(fmaxf(hi[0],0.f), fmaxf(hi[1],0.f)),
              pkrtz(fmaxf(hi[2],0.f), fmaxf(hi[3],0.f)) };
  return t;
}
// lgkm-only barrier: LDS ordering without draining vmcnt (keeps prefetch in flight)
#define LGKM_BAR() do {                                         \
  asm volatile("s_waitcnt lgkmcnt(0)" ::: "memory");            \
  __builtin_amdgcn_s_barrier();                                 \
  __builtin_amdgcn_sched_barrier(0);                            \
} while (0)

// ---- pack W^T -> A-fragment layout (HW-verified R4), LDS-staged ----
__global__ __launch_bounds__(BLOCK) void pack_w2(
    const float* __restrict__ W1, const float* __restrict__ W2,
    const float* __restrict__ W3, uint32_t* __restrict__ ws) {
  __shared__ float wt[DD*DD];
  const int blk = blockIdx.x;
  const int e = blk >> 1, half = blk & 1;
  const float* Wsrc = (half ? W2 : W1) + (size_t)e*DD*DD;
  const float4* s4 = (const float4*)Wsrc;
  float4* d4 = (float4*)wt;
  #pragma unroll
  for (int i = 0; i < DD*DD/4/BLOCK; ++i)
    d4[i*BLOCK + threadIdx.x] = s4[i*BLOCK + threadIdx.x];
  __syncthreads();

  for (int idx = threadIdx.x; idx < 8*64; idx += BLOCK) {
    const int fl = idx >> 6, l = idx & 63;
    const int nt = fl >> 1, ks = fl & 1;
    const int n  = nt*16 + (l & 15), g = l >> 4;
    uint32_t dst[4];
    #pragma unroll
    for (int d = 0; d < 4; ++d) {
      float v[2];
      #pragma unroll
      for (int h = 0; h < 2; ++h) {
        const int kk = 16*(d>>1) + 4*g + 2*(d&1) + h;
        v[h] = wt[(32*ks + kk)*DD + n];
      }
      dst[d] = pkrtz(v[0], v[1]);
    }
    uint32_t* p = ws + ((size_t)(e*NFRAG + half*8 + fl)*64 + l)*4;
    p[0]=dst[0]; p[1]=dst[1]; p[2]=dst[2]; p[3]=dst[3];
  }
  if (half == 0) {
    const float* Wl2 = W3 + (size_t)e*DD*NDC;
    for (int idx = threadIdx.x; idx < 2*64; idx += BLOCK) {
      const int ks = idx >> 6, l = idx & 63;
      const int n  = l & 15, g = l >> 4;
      uint32_t dst[4];
      #pragma unroll
      for (int d = 0; d < 4; ++d) {
        float v[2];
        #pragma unroll
        for (int h = 0; h < 2; ++h) {
          const int kk = 16*(d>>1) + 4*g + 2*(d&1) + h;
          v[h] = (n < NDC) ? Wl2[(32*ks + kk)*NDC + n] : 0.0f;
        }
        dst[d] = pkrtz(v[0], v[1]);
      }
      uint32_t* p = ws + ((size_t)(e*NFRAG + 16 + ks)*64 + l)*4;
      p[0]=dst[0]; p[1]=dst[1]; p[2]=dst[2]; p[3]=dst[3];
    }
  }
}

// ---- fused, 2-chunk software pipeline ----
__global__ __launch_bounds__(BLOCK, 3) void fused(
    const float* __restrict__ X, const int* __restrict__ S,
    const u32x4* __restrict__ wf,
    const float* __restrict__ b1, const float* __restrict__ b2,
    const float* __restrict__ b3,
    float* __restrict__ out, int B)
{
  __shared__ uint32_t pk[2][ROWS*32];    // 2 x 16 KB
  __shared__ float    outbuf[ROWS*6];    // 3 KB
  __shared__ uint16_t srt[2][ROWS];
  __shared__ int wcnt[2][2][NE], woff[2][2][NE], cnt[2][NE];

  const int tid  = threadIdx.x;
  const int wv   = tid >> 6, lane = tid & 63;
  const int r15  = lane & 15, g = lane >> 4;
  const int q    = lane & 15, rsub = lane >> 4;
  const int slotq = 4*(q >> 3) + (q & 3);
  const int hq    = (q >> 2) & 1;
  const int base0 = blockIdx.x * (2*ROWS);
  const int base1 = base0 + ROWS;

  auto ballots = [&](int cbase, int buf, int& e_o, int& p_o) {
    if (wv < 2) {
      e_o = S[cbase + tid];
      unsigned long long mk[NE];
      #pragma unroll
      for (int e = 0; e < NE; ++e) mk[e] = __ballot(e_o == e);
      #pragma unroll
      for (int e = 0; e < NE; ++e)
        if (e_o == e) p_o = __popcll(mk[e] & ((1ull << lane) - 1ull));
      if (lane < NE) wcnt[buf][wv][lane] = __popcll(mk[lane]);
    }
  };
  auto bload = [&](int cbase, float4* raw) {
    const float4* Xb = (const float4*)(X + (size_t)cbase * DD);
    #pragma unroll
    for (int it = 0; it < 8; ++it)
      raw[it] = Xb[(wv*32 + it*4 + rsub)*16 + q];   // 1-KB contiguous per instr
  };
  auto bwrite = [&](int buf, const float4* raw) {
    #pragma unroll
    for (int it = 0; it < 8; ++it) {
      const int r = wv*32 + it*4 + rsub;
      u32x2 w2 = { pkrtz(raw[it].x, raw[it].y), pkrtz(raw[it].z, raw[it].w) };
      *(u32x2*)&pk[buf][r*32 + ((slotq ^ (r & 7)) << 2) + hq*2] = w2;
    }
  };
  auto scan = [&](int buf) {
    if (tid == 0) {
      int acc = 0;
      for (int e = 0; e < NE; ++e) {
        const int s0 = acc;
        for (int w = 0; w < 2; ++w) { woff[buf][w][e] = acc; acc += wcnt[buf][w][e]; }
        cnt[buf][e] = acc - s0;
      }
    }
  };
  auto scatter = [&](int buf, int e_i, int pref) {
    if (wv < 2) srt[buf][woff[buf][wv][e_i] + pref] = (uint16_t)tid;
  };

  auto compute = [&](int buf) {
    int pst[NE + 1];
    int tp = 0;
    #pragma unroll
    for (int e = 0; e < NE; ++e) { pst[e] = tp; tp += (cnt[buf][e] + 31) >> 5; }
    pst[NE] = tp;

    for (int p = wv; p < pst[NE]; p += 4) {
      int e = 0;
      #pragma unroll
      for (int q2 = 1; q2 < NE; ++q2) if (p >= pst[q2]) e = q2;
      const int ch    = p - pst[e];
      const int m     = min(32, cnt[buf][e] - ch*32);
      const int sbase = woff[buf][0][e] + ch*32;
      const int njt   = (m > 16) ? 2 : 1;

      const u32x4* wse = wf + (size_t)e*NFRAG*64;
      u32x4 afA[8];
      #pragma unroll
      for (int f = 0; f < 8; ++f) afA[f] = wse[f*64 + lane];

      int lr[2] = {0, 0};
      u32x4 xf[2][2];
      #pragma unroll
      for (int jt = 0; jt < 2; ++jt) {
        if (jt >= njt) break;
        const int idx16 = min(jt*16 + r15, m - 1);
        lr[jt] = srt[buf][sbase + idx16];
        xf[jt][0] = *(const u32x4*)&pk[buf][lr[jt]*32 + (((    g) ^ (lr[jt] & 7)) << 2)];
        xf[jt][1] = *(const u32x4*)&pk[buf][lr[jt]*32 + (((4 + g) ^ (lr[jt] & 7)) << 2)];
      }

      u32x4 h[2][2];
      #pragma unroll
      for (int jt = 0; jt < 2; ++jt) {
        if (jt >= njt) break;
        f32x4 c[4];
        #pragma unroll
        for (int nt = 0; nt < 4; ++nt) {
          const float4 bv = *(const float4*)(b1 + e*DD + nt*16 + 4*g);
          f32x4 acc = { bv.x, bv.y, bv.z, bv.w };
          acc = mfma16(afA[nt*2 + 0], xf[jt][0], acc);
          acc = mfma16(afA[nt*2 + 1], xf[jt][1], acc);
          c[nt] = acc;
        }
        h[jt][0] = relu_pack(c[0], c[1]);
        h[jt][1] = relu_pack(c[2], c[3]);
      }

      #pragma unroll
      for (int f = 0; f < 8; ++f) afA[f] = wse[(8 + f)*64 + lane];

      u32x4 t[2][2];
      #pragma unroll
      for (int jt = 0; jt < 2; ++jt) {
        if (jt >= njt) break;
        f32x4 c[4];
        #pragma unroll
        for (int nt = 0; nt < 4; ++nt) {
          const float4 bv = *(const float4*)(b2 + e*DD + nt*16 + 4*g);
          f32x4 acc = { bv.x, bv.y, bv.z, bv.w };
          acc = mfma16(afA[nt*2 + 0], h[jt][0], acc);
          acc = mfma16(afA[nt*2 + 1], h[jt][1], acc);
          c[nt] = acc;
        }
        t[jt][0] = relu_pack(c[0], c[1]);
        t[jt][1] = relu_pack(c[2], c[3]);
      }

      const u32x4 a30 = wse[16*64 + lane];
      const u32x4 a31 = wse[17*64 + lane];
      #pragma unroll
      for (int jt = 0; jt < 2; ++jt) {
        if (jt >= njt) break;
        f32x4 acc = { b3[e*NDC + 0], b3[e*NDC + 1], b3[e*NDC + 2], 0.f };
        acc = mfma16(a30, t[jt][0], acc);
        acc = mfma16(a31, t[jt][1], acc);
        if (g == 0 && (jt*16 + r15) < m) {
          const float l0 = acc[0], l1 = acc[1], l2 = acc[2];
          const float mx  = fmaxf(l0, fmaxf(l1, l2));
          const float p0  = __expf(l0 - mx);
          const float p1  = __expf(l1 - mx);
          const float p2  = __expf(l2 - mx);
          const float inv = 1.0f / (p0 + p1 + p2);
          float* ob = outbuf + lr[jt]*6;
          ob[0] = l0;     ob[1] = l1;     ob[2] = l2;
          ob[3] = p0*inv; ob[4] = p1*inv; ob[5] = p2*inv;
        }
      }
    }
  };

  auto dout = [&](int cbase) {
    for (int i = tid; i < ROWS*3; i += BLOCK) {
      const int r = i/3, c2 = i - r*3;
      out[(size_t)cbase*3 + i]                 = outbuf[r*6 + c2];
      out[(size_t)B*3 + (size_t)cbase*3 + i]   = outbuf[r*6 + 3 + c2];
    }
  };

  int e0 = 0, p0 = 0, e1 = 0, p1 = 0;
  float4 raw[8];

  // ---- prologue: stage chunk 0 (latency paid once) ----
  ballots(base0, 0, e0, p0);
  bload(base0, raw);
  bwrite(0, raw);
  __syncthreads();                 // wcnt[0], pk[0] ready
  scan(0);
  LGKM_BAR();                      // woff[0]/cnt[0] visible
  scatter(0, e0, p0);

  // ---- stage chunk 1: ballots + issue loads (kept in regs, stay in flight) ----
  ballots(base1, 1, e1, p1);
  bload(base1, raw);
  LGKM_BAR();                      // srt[0], wcnt[1] visible; raw loads still flying

  // ---- chunk 0 compute while chunk-1 loads fly ----
  compute(0);
  LGKM_BAR();                      // outbuf(0) visible
  dout(base0);

  // ---- finish chunk-1 staging (loads landed during compute) ----
  bwrite(1, raw);
  scan(1);
  __syncthreads();                 // pk[1], woff[1]/cnt[1] ready; outbuf free
  scatter(1, e1, p1);
  LGKM_BAR();                      // srt[1] visible
  compute(1);
  LGKM_BAR();                      // outbuf(1) visible
  dout(base1);
}

extern "C" void kernel_launch(void* const* d_in, const int* in_sizes, int n_in,
                              void* d_out, int out_size, void* d_ws, size_t ws_size,
                              hipStream_t stream)
{
  const float* X  = (const float*)d_in[0];
  const int*   S  = (const int*)d_in[1];
  const float* W1 = (const float*)d_in[2];
  const float* B1 = (const float*)d_in[3];
  const float* W2 = (const float*)d_in[4];
  const float* B2 = (const float*)d_in[5];
  const float* W3 = (const float*)d_in[6];
  const float* B3 = (const float*)d_in[7];
  float* out = (float*)d_out;
  uint32_t* ws = (uint32_t*)d_ws;

  const int B = in_sizes[0] / DD;   // 262144

  pack_w2<<<NE*2, BLOCK, 0, stream>>>(W1, W2, W3, ws);
  fused<<<B / (2*ROWS), BLOCK, 0, stream>>>(X, S, (const u32x4*)ws,
                                            B1, B2, B3, out, B);
}

// Round 16
// 41.333 us; speedup vs baseline: 1.8445x; 1.0146x over previous
//
#include <hip/hip_runtime.h>
#include <stdint.h>

#define NE    7
#define DD    64
#define NDC   3
#define BLOCK 448       // 7 waves: wave w = expert w
#define ROWS  256       // rows per block; B = 1024*256
#define NFRAG 18

typedef __fp16   half8 __attribute__((ext_vector_type(8)));
typedef float    f32x4 __attribute__((ext_vector_type(4)));
typedef uint32_t u32x4 __attribute__((ext_vector_type(4)));
typedef uint32_t u32x2 __attribute__((ext_vector_type(2)));
typedef __fp16   h2_t  __attribute__((ext_vector_type(2)));

__device__ __forceinline__ uint32_t pkrtz(float a, float b) {
  h2_t h = __builtin_amdgcn_cvt_pkrtz(a, b);
  return __builtin_bit_cast(uint32_t, h);
}
__device__ __forceinline__ f32x4 mfma16(u32x4 a, u32x4 b, f32x4 c) {
  return __builtin_amdgcn_mfma_f32_16x16x32_f16(
      __builtin_bit_cast(half8, a), __builtin_bit_cast(half8, b), c, 0, 0, 0);
}
__device__ __forceinline__ u32x4 relu_pack(f32x4 lo, f32x4 hi) {
  u32x4 t = { pkrtz(fmaxf(lo[0],0.f), fmaxf(lo[1],0.f)),
              pkrtz(fmaxf(lo[2],0.f), fmaxf(lo[3],0.f)),
              pkrtz(fmaxf(hi[0],0.f), fmaxf(hi[1],0.f)),
              pkrtz(fmaxf(hi[2],0.f), fmaxf(hi[3],0.f)) };
  return t;
}

// ---- pack W^T -> A-fragment layout (HW-verified R4), LDS-staged ----
__global__ __launch_bounds__(256) void pack_w2(
    const float* __restrict__ W1, const float* __restrict__ W2,
    const float* __restrict__ W3, uint32_t* __restrict__ ws) {
  __shared__ float wt[DD*DD];
  const int blk = blockIdx.x;
  const int e = blk >> 1, half = blk & 1;
  const float* Wsrc = (half ? W2 : W1) + (size_t)e*DD*DD;
  const float4* s4 = (const float4*)Wsrc;
  float4* d4 = (float4*)wt;
  #pragma unroll
  for (int i = 0; i < DD*DD/4/256; ++i)
    d4[i*256 + threadIdx.x] = s4[i*256 + threadIdx.x];
  __syncthreads();

  for (int idx = threadIdx.x; idx < 8*64; idx += 256) {
    const int fl = idx >> 6, l = idx & 63;
    const int nt = fl >> 1, ks = fl & 1;
    const int n  = nt*16 + (l & 15), g = l >> 4;
    uint32_t dst[4];
    #pragma unroll
    for (int d = 0; d < 4; ++d) {
      float v[2];
      #pragma unroll
      for (int h = 0; h < 2; ++h) {
        const int kk = 16*(d>>1) + 4*g + 2*(d&1) + h;
        v[h] = wt[(32*ks + kk)*DD + n];
      }
      dst[d] = pkrtz(v[0], v[1]);
    }
    uint32_t* p = ws + ((size_t)(e*NFRAG + half*8 + fl)*64 + l)*4;
    p[0]=dst[0]; p[1]=dst[1]; p[2]=dst[2]; p[3]=dst[3];
  }
  if (half == 0) {
    const float* Wl2 = W3 + (size_t)e*DD*NDC;
    for (int idx = threadIdx.x; idx < 2*64; idx += 256) {
      const int ks = idx >> 6, l = idx & 63;
      const int n  = l & 15, g = l >> 4;
      uint32_t dst[4];
      #pragma unroll
      for (int d = 0; d < 4; ++d) {
        float v[2];
        #pragma unroll
        for (int h = 0; h < 2; ++h) {
          const int kk = 16*(d>>1) + 4*g + 2*(d&1) + h;
          v[h] = (n < NDC) ? Wl2[(32*ks + kk)*NDC + n] : 0.0f;
        }
        dst[d] = pkrtz(v[0], v[1]);
      }
      uint32_t* p = ws + ((size_t)(e*NFRAG + 16 + ks)*64 + l)*4;
      p[0]=dst[0]; p[1]=dst[1]; p[2]=dst[2]; p[3]=dst[3];
    }
  }
}

// ---- fused: wave = expert; af loaded once; register-resident MFMA subpasses ----
__global__ __launch_bounds__(BLOCK, 4) void fused(
    const float* __restrict__ X, const int* __restrict__ S,
    const u32x4* __restrict__ wf,
    const float* __restrict__ b1, const float* __restrict__ b2,
    const float* __restrict__ b3,
    float* __restrict__ out, int B)
{
  __shared__ uint32_t pk[ROWS*32];     // 32 KB packed fp16 X, slot-swizzled
  __shared__ float    outbuf[ROWS*6];  // 6 KB
  __shared__ uint16_t srt[ROWS];
  __shared__ int wcnt[4][NE], woff[4][NE], cnt[NE];

  const int tid  = threadIdx.x;
  const int wv   = tid >> 6, lane = tid & 63;
  const int r15  = lane & 15, g = lane >> 4;
  const int base = blockIdx.x * ROWS;
  const int e    = wv;                 // wave = expert

  // ---- af: this wave's expert fragments, issued FIRST (fly under staging) ----
  const u32x4* wse = wf + (size_t)e*NFRAG*64;
  u32x4 af[NFRAG];
  #pragma unroll
  for (int f = 0; f < NFRAG; ++f) af[f] = wse[f*64 + lane];

  // ---- A1: route ballots (waves 0-3 own the 256 rows) ----
  int e_i = 0, myprefix = 0;
  if (wv < 4) {
    e_i = S[base + tid];
    unsigned long long mk[NE];
    #pragma unroll
    for (int q2 = 0; q2 < NE; ++q2) mk[q2] = __ballot(e_i == q2);
    #pragma unroll
    for (int q2 = 0; q2 < NE; ++q2)
      if (e_i == q2) myprefix = __popcll(mk[q2] & ((1ull << lane) - 1ull));
    if (lane < NE) wcnt[wv][lane] = __popcll(mk[lane]);
  }

  // ---- B: X -> pk, flat grid-stride (7-KB contiguous windows), fp16 pack ----
  {
    const float4* Xb = (const float4*)(X + (size_t)base * DD);
    #pragma unroll
    for (int ii = 0; ii < 10; ++ii) {
      const int i = ii*BLOCK + tid;
      if (ii == 9 && i >= ROWS*16) break;
      const int r = i >> 4, q = i & 15;
      const float4 v = Xb[i];
      const int slotq = 4*(q >> 3) + (q & 3);
      const int hq    = (q >> 2) & 1;
      u32x2 w2 = { pkrtz(v.x, v.y), pkrtz(v.z, v.w) };
      *(u32x2*)&pk[r*32 + ((slotq ^ (r & 7)) << 2) + hq*2] = w2;
    }
  }
  __syncthreads();

  // ---- A2: serial scan ----
  if (tid == 0) {
    int acc = 0;
    for (int q2 = 0; q2 < NE; ++q2) {
      const int s0 = acc;
      for (int w = 0; w < 4; ++w) { woff[w][q2] = acc; acc += wcnt[w][q2]; }
      cnt[q2] = acc - s0;
    }
  }
  __syncthreads();

  // ---- A3: scatter sorted list ----
  if (wv < 4) srt[woff[wv][e_i] + myprefix] = (uint16_t)tid;
  __syncthreads();

  // ---- C: this wave's expert, 16-row register-resident subpasses ----
  const int cn    = cnt[e];
  const int sbase = woff[0][e];
  const float4 bv1[4] = { *(const float4*)(b1 + e*DD +  0 + 4*g),
                          *(const float4*)(b1 + e*DD + 16 + 4*g),
                          *(const float4*)(b1 + e*DD + 32 + 4*g),
                          *(const float4*)(b1 + e*DD + 48 + 4*g) };
  const float4 bv2[4] = { *(const float4*)(b2 + e*DD +  0 + 4*g),
                          *(const float4*)(b2 + e*DD + 16 + 4*g),
                          *(const float4*)(b2 + e*DD + 32 + 4*g),
                          *(const float4*)(b2 + e*DD + 48 + 4*g) };
  const float bb0 = b3[e*NDC+0], bb1 = b3[e*NDC+1], bb2 = b3[e*NDC+2];

  for (int r0 = 0; r0 < cn; r0 += 16) {
    const int m  = cn - r0;                       // rows left (use min(m,16))
    const int lr = srt[sbase + r0 + min(r15, m - 1)];

    // B-fragments from LDS
    const u32x4 xf0 = *(const u32x4*)&pk[lr*32 + (((    g) ^ (lr & 7)) << 2)];
    const u32x4 xf1 = *(const u32x4*)&pk[lr*32 + (((4 + g) ^ (lr & 7)) << 2)];

    // Layer 1
    f32x4 c[4];
    #pragma unroll
    for (int nt = 0; nt < 4; ++nt) {
      f32x4 acc = { bv1[nt].x, bv1[nt].y, bv1[nt].z, bv1[nt].w };
      acc = mfma16(af[nt*2 + 0], xf0, acc);
      acc = mfma16(af[nt*2 + 1], xf1, acc);
      c[nt] = acc;
    }
    const u32x4 h0 = relu_pack(c[0], c[1]);
    const u32x4 h1 = relu_pack(c[2], c[3]);

    // Layer 2
    #pragma unroll
    for (int nt = 0; nt < 4; ++nt) {
      f32x4 acc = { bv2[nt].x, bv2[nt].y, bv2[nt].z, bv2[nt].w };
      acc = mfma16(af[8 + nt*2 + 0], h0, acc);
      acc = mfma16(af[8 + nt*2 + 1], h1, acc);
      c[nt] = acc;
    }
    const u32x4 t0 = relu_pack(c[0], c[1]);
    const u32x4 t1 = relu_pack(c[2], c[3]);

    // Layer 3 + softmax
    f32x4 acc = { bb0, bb1, bb2, 0.f };
    acc = mfma16(af[16], t0, acc);
    acc = mfma16(af[17], t1, acc);

    if (g == 0 && r15 < m) {
      const float l0 = acc[0], l1 = acc[1], l2 = acc[2];
      const float mx  = fmaxf(l0, fmaxf(l1, l2));
      const float p0  = __expf(l0 - mx);
      const float p1  = __expf(l1 - mx);
      const float p2  = __expf(l2 - mx);
      const float inv = 1.0f / (p0 + p1 + p2);
      float* ob = outbuf + lr*6;
      ob[0] = l0;     ob[1] = l1;     ob[2] = l2;
      ob[3] = p0*inv; ob[4] = p1*inv; ob[5] = p2*inv;
    }
  }
  __syncthreads();

  // ---- D: coalesced output (768 floats x 2 streams, 2 strided iters) ----
  for (int i = tid; i < ROWS*3; i += BLOCK) {
    const int r = i/3, c2 = i - r*3;
    out[(size_t)base*3 + i]               = outbuf[r*6 + c2];
    out[(size_t)B*3 + (size_t)base*3 + i] = outbuf[r*6 + 3 + c2];
  }
}

extern "C" void kernel_launch(void* const* d_in, const int* in_sizes, int n_in,
                              void* d_out, int out_size, void* d_ws, size_t ws_size,
                              hipStream_t stream)
{
  const float* X  = (const float*)d_in[0];
  const int*   S  = (const int*)d_in[1];
  const float* W1 = (const float*)d_in[2];
  const float* B1 = (const float*)d_in[3];
  const float* W2 = (const float*)d_in[4];
  const float* B2 = (const float*)d_in[5];
  const float* W3 = (const float*)d_in[6];
  const float* B3 = (const float*)d_in[7];
  float* out = (float*)d_out;
  uint32_t* ws = (uint32_t*)d_ws;

  const int B = in_sizes[0] / DD;   // 262144

  pack_w2<<<NE*2, 256, 0, stream>>>(W1, W2, W3, ws);
  fused<<<B / ROWS, BLOCK, 0, stream>>>(X, S, (const u32x4*)ws,
                                        B1, B2, B3, out, B);
}

// Round 17
// 34.861 us; speedup vs baseline: 2.1869x; 1.1856x over previous
//
#include <hip/hip_runtime.h>
#include <stdint.h>

#define NE    7
#define DD    64
#define NDC   3
#define BLOCK 256
#define ROWS  256       // rows per block; B = 1024*256
#define NFRAG 18

typedef __fp16   half8 __attribute__((ext_vector_type(8)));
typedef float    f32x4 __attribute__((ext_vector_type(4)));
typedef uint32_t u32x4 __attribute__((ext_vector_type(4)));
typedef uint32_t u32x2 __attribute__((ext_vector_type(2)));
typedef __fp16   h2_t  __attribute__((ext_vector_type(2)));

__device__ __forceinline__ uint32_t pkrtz(float a, float b) {
  h2_t h = __builtin_amdgcn_cvt_pkrtz(a, b);
  return __builtin_bit_cast(uint32_t, h);
}
__device__ __forceinline__ f32x4 mfma16(u32x4 a, u32x4 b, f32x4 c) {
  return __builtin_amdgcn_mfma_f32_16x16x32_f16(
      __builtin_bit_cast(half8, a), __builtin_bit_cast(half8, b), c, 0, 0, 0);
}
__device__ __forceinline__ u32x4 relu_pack(f32x4 lo, f32x4 hi) {
  u32x4 t = { pkrtz(fmaxf(lo[0],0.f), fmaxf(lo[1],0.f)),
              pkrtz(fmaxf(lo[2],0.f), fmaxf(lo[3],0.f)),
              pkrtz(fmaxf(hi[0],0.f), fmaxf(hi[1],0.f)),
              pkrtz(fmaxf(hi[2],0.f), fmaxf(hi[3],0.f)) };
  return t;
}

// ---- pack W^T -> A-fragment layout (HW-verified R4), LDS-staged ----
__global__ __launch_bounds__(256) void pack_w2(
    const float* __restrict__ W1, const float* __restrict__ W2,
    const float* __restrict__ W3, uint32_t* __restrict__ ws) {
  __shared__ float wt[DD*DD];
  const int blk = blockIdx.x;
  const int e = blk >> 1, half = blk & 1;
  const float* Wsrc = (half ? W2 : W1) + (size_t)e*DD*DD;
  const float4* s4 = (const float4*)Wsrc;
  float4* d4 = (float4*)wt;
  #pragma unroll
  for (int i = 0; i < DD*DD/4/256; ++i)
    d4[i*256 + threadIdx.x] = s4[i*256 + threadIdx.x];
  __syncthreads();

  for (int idx = threadIdx.x; idx < 8*64; idx += 256) {
    const int fl = idx >> 6, l = idx & 63;
    const int nt = fl >> 1, ks = fl & 1;
    const int n  = nt*16 + (l & 15), g = l >> 4;
    uint32_t dst[4];
    #pragma unroll
    for (int d = 0; d < 4; ++d) {
      float v[2];
      #pragma unroll
      for (int h = 0; h < 2; ++h) {
        const int kk = 16*(d>>1) + 4*g + 2*(d&1) + h;
        v[h] = wt[(32*ks + kk)*DD + n];
      }
      dst[d] = pkrtz(v[0], v[1]);
    }
    uint32_t* p = ws + ((size_t)(e*NFRAG + half*8 + fl)*64 + l)*4;
    p[0]=dst[0]; p[1]=dst[1]; p[2]=dst[2]; p[3]=dst[3];
  }
  if (half == 0) {
    const float* Wl2 = W3 + (size_t)e*DD*NDC;
    for (int idx = threadIdx.x; idx < 2*64; idx += 256) {
      const int ks = idx >> 6, l = idx & 63;
      const int n  = l & 15, g = l >> 4;
      uint32_t dst[4];
      #pragma unroll
      for (int d = 0; d < 4; ++d) {
        float v[2];
        #pragma unroll
        for (int h = 0; h < 2; ++h) {
          const int kk = 16*(d>>1) + 4*g + 2*(d&1) + h;
          v[h] = (n < NDC) ? Wl2[(32*ks + kk)*NDC + n] : 0.0f;
        }
        dst[d] = pkrtz(v[0], v[1]);
      }
      uint32_t* p = ws + ((size_t)(e*NFRAG + 16 + ks)*64 + l)*4;
      p[0]=dst[0]; p[1]=dst[1]; p[2]=dst[2]; p[3]=dst[3];
    }
  }
}

// ---- fused: wave-static experts; af prefetched at entry; 16-row subpasses ----
__global__ __launch_bounds__(BLOCK, 3) void fused(
    const float* __restrict__ X, const int* __restrict__ S,
    const u32x4* __restrict__ wf,
    const float* __restrict__ b1, const float* __restrict__ b2,
    const float* __restrict__ b3,
    float* __restrict__ out, int B)
{
  __shared__ uint32_t pk[ROWS*32];     // 32 KB packed fp16 X, slot-swizzled
  __shared__ float    outbuf[ROWS*6];  // 6 KB
  __shared__ uint16_t srt[ROWS];
  __shared__ int wcnt[4][NE], woff[4][NE], cnt[NE];

  const int tid  = threadIdx.x;
  const int wv   = tid >> 6, lane = tid & 63;
  const int r15  = lane & 15, g = lane >> 4;
  const int base = blockIdx.x * ROWS;

  // ---- af prefetch for primary expert (= wv): issued first, lands during prologue ----
  u32x4 af[NFRAG];
  {
    const u32x4* wse = wf + (size_t)wv*NFRAG*64;
    #pragma unroll
    for (int f = 0; f < NFRAG; ++f) af[f] = wse[f*64 + lane];
  }

  // ---- A1: route ballots (each thread owns row tid) ----
  const int e_i = S[base + tid];
  int myprefix = 0;
  {
    unsigned long long mk[NE];
    #pragma unroll
    for (int q2 = 0; q2 < NE; ++q2) mk[q2] = __ballot(e_i == q2);
    #pragma unroll
    for (int q2 = 0; q2 < NE; ++q2)
      if (e_i == q2) myprefix = __popcll(mk[q2] & ((1ull << lane) - 1ull));
    if (lane < NE) wcnt[wv][lane] = __popcll(mk[lane]);
  }

  // ---- B: X -> pk (4-KB contiguous per block-instr), fp16 pack, slot-swizzle ----
  {
    const float4* Xb = (const float4*)(X + (size_t)base * DD);
    #pragma unroll
    for (int it = 0; it < 16; ++it) {
      const int i = it*BLOCK + tid;
      const int r = i >> 4, q = i & 15;
      const float4 v = Xb[i];
      const int slotq = 4*(q >> 3) + (q & 3);
      const int hq    = (q >> 2) & 1;
      u32x2 w2 = { pkrtz(v.x, v.y), pkrtz(v.z, v.w) };
      *(u32x2*)&pk[r*32 + ((slotq ^ (r & 7)) << 2) + hq*2] = w2;
    }
  }
  __syncthreads();

  // ---- A2: serial scan ----
  if (tid == 0) {
    int acc = 0;
    for (int q2 = 0; q2 < NE; ++q2) {
      const int s0 = acc;
      for (int w = 0; w < 4; ++w) { woff[w][q2] = acc; acc += wcnt[w][q2]; }
      cnt[q2] = acc - s0;
    }
  }
  __syncthreads();

  // ---- A3: scatter sorted list ----
  srt[woff[wv][e_i] + myprefix] = (uint16_t)tid;
  __syncthreads();

  // ---- C: wave-static experts (wv, then wv+4 for wv<3); register-resident subpasses ----
  auto run_expert = [&](int e, const u32x4 (&A)[NFRAG]) {
    const int cn    = cnt[e];
    const int sbase = woff[0][e];
    const float4 bv1[4] = { *(const float4*)(b1 + e*DD +  0 + 4*g),
                            *(const float4*)(b1 + e*DD + 16 + 4*g),
                            *(const float4*)(b1 + e*DD + 32 + 4*g),
                            *(const float4*)(b1 + e*DD + 48 + 4*g) };
    const float4 bv2[4] = { *(const float4*)(b2 + e*DD +  0 + 4*g),
                            *(const float4*)(b2 + e*DD + 16 + 4*g),
                            *(const float4*)(b2 + e*DD + 32 + 4*g),
                            *(const float4*)(b2 + e*DD + 48 + 4*g) };
    const float bb0 = b3[e*NDC+0], bb1 = b3[e*NDC+1], bb2 = b3[e*NDC+2];

    for (int r0 = 0; r0 < cn; r0 += 16) {
      const int m  = cn - r0;
      const int lr = srt[sbase + r0 + min(r15, m - 1)];

      const u32x4 xf0 = *(const u32x4*)&pk[lr*32 + (((    g) ^ (lr & 7)) << 2)];
      const u32x4 xf1 = *(const u32x4*)&pk[lr*32 + (((4 + g) ^ (lr & 7)) << 2)];

      f32x4 c[4];
      #pragma unroll
      for (int nt = 0; nt < 4; ++nt) {
        f32x4 acc = { bv1[nt].x, bv1[nt].y, bv1[nt].z, bv1[nt].w };
        acc = mfma16(A[nt*2 + 0], xf0, acc);
        acc = mfma16(A[nt*2 + 1], xf1, acc);
        c[nt] = acc;
      }
      const u32x4 h0 = relu_pack(c[0], c[1]);
      const u32x4 h1 = relu_pack(c[2], c[3]);

      #pragma unroll
      for (int nt = 0; nt < 4; ++nt) {
        f32x4 acc = { bv2[nt].x, bv2[nt].y, bv2[nt].z, bv2[nt].w };
        acc = mfma16(A[8 + nt*2 + 0], h0, acc);
        acc = mfma16(A[8 + nt*2 + 1], h1, acc);
        c[nt] = acc;
      }
      const u32x4 t0 = relu_pack(c[0], c[1]);
      const u32x4 t1 = relu_pack(c[2], c[3]);

      f32x4 acc = { bb0, bb1, bb2, 0.f };
      acc = mfma16(A[16], t0, acc);
      acc = mfma16(A[17], t1, acc);

      if (g == 0 && r15 < m) {
        const float l0 = acc[0], l1 = acc[1], l2 = acc[2];
        const float mx  = fmaxf(l0, fmaxf(l1, l2));
        const float p0  = __expf(l0 - mx);
        const float p1  = __expf(l1 - mx);
        const float p2  = __expf(l2 - mx);
        const float inv = 1.0f / (p0 + p1 + p2);
        float* ob = outbuf + lr*6;
        ob[0] = l0;     ob[1] = l1;     ob[2] = l2;
        ob[3] = p0*inv; ob[4] = p1*inv; ob[5] = p2*inv;
      }
    }
  };

  run_expert(wv, af);

  if (wv < 3) {
    const int e2 = wv + 4;
    const u32x4* wse2 = wf + (size_t)e2*NFRAG*64;
    #pragma unroll
    for (int f = 0; f < NFRAG; ++f) af[f] = wse2[f*64 + lane];   // one exposed reload
    run_expert(e2, af);
  }
  __syncthreads();

  // ---- D: coalesced output (768 floats x 2 streams, 3 strided iters) ----
  #pragma unroll
  for (int it = 0; it < 3; ++it) {
    const int i = it*BLOCK + tid;
    const int r = i/3, c2 = i - r*3;
    out[(size_t)base*3 + i]               = outbuf[r*6 + c2];
    out[(size_t)B*3 + (size_t)base*3 + i] = outbuf[r*6 + 3 + c2];
  }
}

extern "C" void kernel_launch(void* const* d_in, const int* in_sizes, int n_in,
                              void* d_out, int out_size, void* d_ws, size_t ws_size,
                              hipStream_t stream)
{
  const float* X  = (const float*)d_in[0];
  const int*   S  = (const int*)d_in[1];
  const float* W1 = (const float*)d_in[2];
  const float* B1 = (const float*)d_in[3];
  const float* W2 = (const float*)d_in[4];
  const float* B2 = (const float*)d_in[5];
  const float* W3 = (const float*)d_in[6];
  const float* B3 = (const float*)d_in[7];
  float* out = (float*)d_out;
  uint32_t* ws = (uint32_t*)d_ws;

  const int B = in_sizes[0] / DD;   // 262144

  pack_w2<<<NE*2, 256, 0, stream>>>(W1, W2, W3, ws);
  fused<<<B / ROWS, BLOCK, 0, stream>>>(X, S, (const u32x4*)ws,
                                        B1, B2, B3, out, B);
}